// Round 1
// 1464.508 us; speedup vs baseline: 1.2849x; 1.2849x over previous
//
#include <hip/hip_runtime.h>
#include <hip/hip_bf16.h>
#include <cstddef>
#include <cstdint>

// ---------------- problem constants ----------------
constexpr int B = 2, L = 2048, DIM = 2048;
constexpr int HK = 16, HV = 32, DK = 128, DV = 128;
constexpr int KEY_DIM = HK * DK;                    // 2048
constexpr int VAL_DIM = HV * DV;                    // 4096
constexpr int CONV_DIM = 2 * KEY_DIM + VAL_DIM;     // 8192
constexpr int NPROJ = CONV_DIM + VAL_DIM + HV + HV; // 12352
constexpr size_t ROWS = (size_t)B * L;              // 4096
constexpr float EPS = 1e-6f;
constexpr int CHUNK = 64, NCHUNK = L / CHUNK;       // 32 chunks
constexpr int NCH_TOT = B * HV * NCHUNK;            // 2048 chunk-head blocks

// workspace layout (BYTE offsets). Total ~187 MB.
constexpr size_t OFF_QKV  = 0;                                   // bf16
constexpr size_t OFF_Z    = OFF_QKV + ROWS * CONV_DIM * 2;       // bf16 (y in-place)
constexpr size_t OFF_A    = OFF_Z   + ROWS * VAL_DIM * 2;        // f32
constexpr size_t OFF_B    = OFF_A   + ROWS * HV * 4;
constexpr size_t OFF_G    = OFF_B   + ROWS * HV * 4;             // g (log-space)
constexpr size_t OFF_BETA = OFF_G   + ROWS * HV * 4;
constexpr size_t OFF_U    = OFF_BETA + ROWS * HV * 4;            // f32 U = T(BV)
constexpr size_t OFF_WQK  = OFF_U + (size_t)NCH_TOT * CHUNK * DV * 4;  // bf16 Wqk
constexpr size_t WS_NEED_BYTES = OFF_WQK + (size_t)NCH_TOT * CHUNK * CHUNK * 2;

// ---------------- bf16 helpers ----------------
__device__ __forceinline__ float bf2f(unsigned short u) {
    union { float f; uint32_t i; } c; c.i = ((uint32_t)u) << 16; return c.f;
}
__device__ __forceinline__ unsigned short f2bf(float f) {
    union { float f; uint32_t u; } c; c.f = f;
    uint32_t u = c.u + 0x7FFFu + ((c.u >> 16) & 1u);   // RTNE
    return (unsigned short)(u >> 16);
}
__device__ __forceinline__ uint32_t pk2(float a, float b) {
    return (uint32_t)f2bf(a) | ((uint32_t)f2bf(b) << 16);
}

// MFMA fragment types (16x16x32 bf16)
typedef __attribute__((ext_vector_type(8))) short bfrag;   // 8 bf16
typedef __attribute__((ext_vector_type(4))) float ffrag;   // 4 f32

constexpr int SA = 40;   // GEMM LDS row stride (bf16)

// ================= in-projection MFMA GEMM =================
__device__ __forceinline__ const float* w_row_multi(int n, const float* Wq, const float* Wz,
                                                    const float* Wa, const float* Wb) {
    if (n < CONV_DIM)                return Wq + (size_t)n * DIM;
    if (n < CONV_DIM + VAL_DIM)      return Wz + (size_t)(n - CONV_DIM) * DIM;
    if (n < CONV_DIM + VAL_DIM + HV) return Wa + (size_t)(n - CONV_DIM - VAL_DIM) * DIM;
    return Wb + (size_t)(n - CONV_DIM - VAL_DIM - HV) * DIM;
}

__device__ __forceinline__ void store_multi(int m, int n, float v,
                                            unsigned short* qkv, unsigned short* z,
                                            float* a, float* b) {
    if (n < CONV_DIM) {
        qkv[(size_t)m * CONV_DIM + n] = f2bf(v);
    } else if (n < CONV_DIM + VAL_DIM) {
        z[(size_t)m * VAL_DIM + (n - CONV_DIM)] = f2bf(v);
    } else if (n < CONV_DIM + VAL_DIM + HV) {
        a[(size_t)m * HV + (n - CONV_DIM - VAL_DIM)] = v;
    } else if (n < NPROJ) {
        b[(size_t)m * HV + (n - CONV_DIM - VAL_DIM - HV)] = v;
    }
}

__global__ __launch_bounds__(256) void gemm_inproj(
    const float* __restrict__ x,
    const float* __restrict__ Wq, const float* __restrict__ Wz,
    const float* __restrict__ Wa, const float* __restrict__ Wb,
    unsigned short* __restrict__ qkv, unsigned short* __restrict__ z,
    float* __restrict__ a_out, float* __restrict__ b_out)
{
    __shared__ __align__(16) unsigned short As[128 * SA];
    __shared__ __align__(16) unsigned short Ws[128 * SA];

    const int t    = threadIdx.x;
    const int row0 = blockIdx.y * 128;
    const int col0 = blockIdx.x * 128;
    const int r    = t >> 1;
    const int kh   = (t & 1) * 16;
    const int lane = t & 63;
    const int wid  = t >> 6;
    const int wm   = (wid >> 1) * 64;
    const int wn   = (wid & 1) * 64;
    const int quad = lane >> 4;
    const int l16  = lane & 15;

    ffrag acc[4][4];
#pragma unroll
    for (int i = 0; i < 4; ++i)
#pragma unroll
        for (int j = 0; j < 4; ++j) acc[i][j] = (ffrag)0.f;

    const float* aP = x + (size_t)(row0 + r) * DIM + kh;
    const int wr = col0 + r;
    const float* wP = ((wr < NPROJ) ? w_row_multi(wr, Wq, Wz, Wa, Wb) : Wq) + kh;

    const int aoff = r * SA + kh;
    const int fa   = (wm + l16) * SA + quad * 8;
    const int fb   = (wn + l16) * SA + quad * 8;

    for (int k0 = 0; k0 < DIM; k0 += 32) {
        float4 av0 = *(const float4*)(aP + k0);
        float4 av1 = *(const float4*)(aP + k0 + 4);
        float4 av2 = *(const float4*)(aP + k0 + 8);
        float4 av3 = *(const float4*)(aP + k0 + 12);
        float4 wv0 = *(const float4*)(wP + k0);
        float4 wv1 = *(const float4*)(wP + k0 + 4);
        float4 wv2 = *(const float4*)(wP + k0 + 8);
        float4 wv3 = *(const float4*)(wP + k0 + 12);
        __syncthreads();
        *(uint4*)&As[aoff]     = make_uint4(pk2(av0.x, av0.y), pk2(av0.z, av0.w),
                                            pk2(av1.x, av1.y), pk2(av1.z, av1.w));
        *(uint4*)&As[aoff + 8] = make_uint4(pk2(av2.x, av2.y), pk2(av2.z, av2.w),
                                            pk2(av3.x, av3.y), pk2(av3.z, av3.w));
        *(uint4*)&Ws[aoff]     = make_uint4(pk2(wv0.x, wv0.y), pk2(wv0.z, wv0.w),
                                            pk2(wv1.x, wv1.y), pk2(wv1.z, wv1.w));
        *(uint4*)&Ws[aoff + 8] = make_uint4(pk2(wv2.x, wv2.y), pk2(wv2.z, wv2.w),
                                            pk2(wv3.x, wv3.y), pk2(wv3.z, wv3.w));
        __syncthreads();

        bfrag aF[4], bF[4];
#pragma unroll
        for (int mt = 0; mt < 4; ++mt) aF[mt] = *(const bfrag*)&As[fa + mt * 16 * SA];
#pragma unroll
        for (int nt = 0; nt < 4; ++nt) bF[nt] = *(const bfrag*)&Ws[fb + nt * 16 * SA];
#pragma unroll
        for (int mt = 0; mt < 4; ++mt)
#pragma unroll
            for (int nt = 0; nt < 4; ++nt)
                acc[mt][nt] = __builtin_amdgcn_mfma_f32_16x16x32_bf16(
                    aF[mt], bF[nt], acc[mt][nt], 0, 0, 0);
    }

#pragma unroll
    for (int mt = 0; mt < 4; ++mt)
#pragma unroll
        for (int nt = 0; nt < 4; ++nt) {
            int gr = row0 + wm + mt * 16 + quad * 4;
            int gc = col0 + wn + nt * 16 + l16;
#pragma unroll
            for (int reg = 0; reg < 4; ++reg)
                store_multi(gr + reg, gc, acc[mt][nt][reg], qkv, z, a_out, b_out);
        }
}

// ================= out-projection MFMA GEMM =================
__global__ __launch_bounds__(256) void gemm_outproj(
    const unsigned short* __restrict__ A,   // (ROWS, VAL_DIM) bf16
    const float* __restrict__ W,            // (DIM, VAL_DIM) f32
    float* __restrict__ C)                  // (ROWS, DIM) f32
{
    __shared__ __align__(16) unsigned short As[128 * SA];
    __shared__ __align__(16) unsigned short Ws[128 * SA];

    const int t    = threadIdx.x;
    const int row0 = blockIdx.y * 128;
    const int col0 = blockIdx.x * 128;
    const int r    = t >> 1;
    const int kh   = (t & 1) * 16;
    const int lane = t & 63;
    const int wid  = t >> 6;
    const int wm   = (wid >> 1) * 64;
    const int wn   = (wid & 1) * 64;
    const int quad = lane >> 4;
    const int l16  = lane & 15;

    ffrag acc[4][4];
#pragma unroll
    for (int i = 0; i < 4; ++i)
#pragma unroll
        for (int j = 0; j < 4; ++j) acc[i][j] = (ffrag)0.f;

    const unsigned short* aP = A + (size_t)(row0 + r) * VAL_DIM + kh;
    const float* wP = W + (size_t)(col0 + r) * VAL_DIM + kh;

    const int aoff = r * SA + kh;
    const int fa   = (wm + l16) * SA + quad * 8;
    const int fb   = (wn + l16) * SA + quad * 8;

    for (int k0 = 0; k0 < VAL_DIM; k0 += 32) {
        uint4 au0 = *(const uint4*)(aP + k0);
        uint4 au1 = *(const uint4*)(aP + k0 + 8);
        float4 wv0 = *(const float4*)(wP + k0);
        float4 wv1 = *(const float4*)(wP + k0 + 4);
        float4 wv2 = *(const float4*)(wP + k0 + 8);
        float4 wv3 = *(const float4*)(wP + k0 + 12);
        __syncthreads();
        *(uint4*)&As[aoff]     = au0;
        *(uint4*)&As[aoff + 8] = au1;
        *(uint4*)&Ws[aoff]     = make_uint4(pk2(wv0.x, wv0.y), pk2(wv0.z, wv0.w),
                                            pk2(wv1.x, wv1.y), pk2(wv1.z, wv1.w));
        *(uint4*)&Ws[aoff + 8] = make_uint4(pk2(wv2.x, wv2.y), pk2(wv2.z, wv2.w),
                                            pk2(wv3.x, wv3.y), pk2(wv3.z, wv3.w));
        __syncthreads();

        bfrag aF[4], bF[4];
#pragma unroll
        for (int mt = 0; mt < 4; ++mt) aF[mt] = *(const bfrag*)&As[fa + mt * 16 * SA];
#pragma unroll
        for (int nt = 0; nt < 4; ++nt) bF[nt] = *(const bfrag*)&Ws[fb + nt * 16 * SA];
#pragma unroll
        for (int mt = 0; mt < 4; ++mt)
#pragma unroll
            for (int nt = 0; nt < 4; ++nt)
                acc[mt][nt] = __builtin_amdgcn_mfma_f32_16x16x32_bf16(
                    aF[mt], bF[nt], acc[mt][nt], 0, 0, 0);
    }

#pragma unroll
    for (int mt = 0; mt < 4; ++mt)
#pragma unroll
        for (int nt = 0; nt < 4; ++nt) {
            int gr = row0 + wm + mt * 16 + quad * 4;
            int gc = col0 + wn + nt * 16 + l16;
#pragma unroll
            for (int reg = 0; reg < 4; ++reg)
                C[(size_t)(gr + reg) * DIM + gc] = acc[mt][nt][reg];
        }
}

// ================= depthwise causal conv1d + SiLU =================
__global__ __launch_bounds__(256) void conv_silu(unsigned short* __restrict__ qkv,
                                                 const float* __restrict__ conv_w)
{
    int idx = blockIdx.x * blockDim.x + threadIdx.x;
    int b = idx >> 13;
    int c = idx & (CONV_DIM - 1);
    const float w0 = conv_w[c * 4 + 0];
    const float w1 = conv_w[c * 4 + 1];
    const float w2 = conv_w[c * 4 + 2];
    const float w3 = conv_w[c * 4 + 3];
    unsigned short* p = qkv + (size_t)b * L * CONV_DIM + c;
    float x0 = 0.f, x1 = 0.f, x2 = 0.f;
    for (int l0 = 0; l0 < L; l0 += 8) {
        float xv[8];
#pragma unroll
        for (int j = 0; j < 8; ++j) xv[j] = bf2f(p[(size_t)(l0 + j) * CONV_DIM]);
#pragma unroll
        for (int j = 0; j < 8; ++j) {
            float h = w0 * x0 + w1 * x1 + w2 * x2 + w3 * xv[j];
            float s = h / (1.f + __expf(-h));
            p[(size_t)(l0 + j) * CONV_DIM] = f2bf(s);
            x0 = x1; x1 = x2; x2 = xv[j];
        }
    }
}

// ================= l2norm of q,k heads =================
__global__ __launch_bounds__(256) void normqk(unsigned short* __restrict__ qkv)
{
    int wid  = blockIdx.x * 4 + (threadIdx.x >> 6);
    int lane = threadIdx.x & 63;
    int hk  = wid & 15;
    int sel = (wid >> 4) & 1;
    int row = wid >> 5;
    unsigned short* p = qkv + (size_t)row * CONV_DIM + sel * KEY_DIM + hk * DK;
    float x0 = bf2f(p[lane]), x1 = bf2f(p[lane + 64]);
    float ss = x0 * x0 + x1 * x1;
#pragma unroll
    for (int o = 32; o >= 1; o >>= 1) ss += __shfl_xor(ss, o);
    float sc = rsqrtf(ss + 1e-6f);
    if (sel == 0) sc *= 0.08838834764831845f;   // DK^-0.5
    p[lane]      = f2bf(x0 * sc);
    p[lane + 64] = f2bf(x1 * sc);
}

// ================= gate coefficients: g (log) and beta =================
__global__ __launch_bounds__(256) void gatecoef(const float* __restrict__ a_buf,
                                                const float* __restrict__ b_buf,
                                                const float* __restrict__ A_log,
                                                const float* __restrict__ dt_bias,
                                                float* __restrict__ glog,
                                                float* __restrict__ beta)
{
    int idx = blockIdx.x * blockDim.x + threadIdx.x;
    int h = idx & (HV - 1);
    float av = a_buf[idx];
    float bv = b_buf[idx];
    float x  = av + dt_bias[h];
    float sp = (x > 20.f) ? x : log1pf(__expf(x));
    glog[idx] = -__expf(A_log[h]) * sp;
    beta[idx] = 1.f / (1.f + __expf(-bv));
}

// ===================================================================
// Two-pass chunked gated delta rule.
//
// Pass 1 (chunk_prep, parallel over (b,h,ch) = 2048 blocks):
//   A    = beta_i e^{Gi-Gj}(k_i.k_j)           [j<i]
//   Wqk  = e^{Gi-Gj}(q_i.k_j)                  [j<=i]   -> global bf16
//   Solve (I+A) X = [ B*V | B*eG*K ]  (256 columns, 1 thread/col)
//   U    = X[:,0:128]  -> global f32
//   Wkn  = -X[:,128:256] -> overwrites V slot of qkv (bf16)
//
// Pass 2 (chunk_scan2, sequential over chunks, 64 blocks):
//   Delta = U + Wkn . S0^T            (acc preloaded with U)
//   O     = eG*(Q S0) + Wqk . Delta   (fused RMSNorm + silu(z) gate)
//   S1    = eGc S0 + Dd^T K           (Dd_j = e^{Gc-Gj} delta_j)
// ===================================================================

// shared strides
constexpr int RSK  = 136;   // 128-wide bf16 rows (128 data + 8 pad)
constexpr int RST  = 72;    // 64-wide bf16 rows (64 data + 8 pad)
constexpr int RSTD = 68;    // pass-1 X^T rows (64 data + 4 pad)
constexpr int RSR1 = 260;   // pass-1 RHS f32 rows (256 data + 4 pad)
constexpr int RSR2 = 132;   // pass-2 U f32 rows (128 data + 4 pad)

// ---- pass-1 LDS layout ----
constexpr int P1_oKs  = 0;                       // 64*136*2 = 17408
constexpr int P1_oQs  = P1_oKs + 64 * RSK * 2;   // 17408
constexpr int P1_oDT  = 0;                       // overlay Ks+Qs: 256*68*2 = 34816
constexpr int P1_oAf  = P1_oQs + 64 * RSK * 2;   // 34816 (64*72*2 = 9216)
constexpr int P1_oRHS = P1_oAf + 64 * RST * 2;   // 44032 (64*260*4 = 66560)
constexpr int P1_oG   = P1_oRHS + 64 * RSR1 * 4; // 110592
constexpr int P1_oEG  = P1_oG + 256;
constexpr int P1_oBs  = P1_oEG + 256;
constexpr int P1_SMEM = P1_oBs + 256;            // 111616

__global__ __launch_bounds__(256, 1) void chunk_prep(
    unsigned short* __restrict__ qkv,     // v-slot overwritten with Wkn
    const float* __restrict__ glog,
    const float* __restrict__ beta,
    float* __restrict__ Ubuf,
    unsigned short* __restrict__ Wqkbuf)
{
    extern __shared__ __align__(16) char smem[];
    unsigned short* sKs = (unsigned short*)(smem + P1_oKs);
    unsigned short* sQs = (unsigned short*)(smem + P1_oQs);
    unsigned short* sDT = (unsigned short*)(smem + P1_oDT);
    unsigned short* sAf = (unsigned short*)(smem + P1_oAf);
    float* sRHS = (float*)(smem + P1_oRHS);
    float* sG   = (float*)(smem + P1_oG);
    float* sEG  = (float*)(smem + P1_oEG);
    float* sBs  = (float*)(smem + P1_oBs);

    const int bid = blockIdx.x;
    const int ch = bid & (NCHUNK - 1);
    const int h  = (bid >> 5) & (HV - 1);
    const int bb = bid >> 10;
    const int hk = h >> 1;
    const int t    = threadIdx.x;
    const int w    = t >> 6;
    const int lane = t & 63;
    const int quad = lane >> 4;
    const int l16  = lane & 15;
    const int quad8 = quad * 8;
    const size_t bL = (size_t)bb * L;
    const int l0 = ch * CHUNK;
    const int VOFF = 2 * KEY_DIM + h * DV;

    // ---- loads ----
    {
        const int r  = t >> 2;
        const int c0 = (t & 3) * 32;
        const unsigned short* grow = qkv + (bL + l0 + r) * CONV_DIM;
        const unsigned short* gq = grow + hk * DK + c0;
        const unsigned short* gk = grow + KEY_DIM + hk * DK + c0;
#pragma unroll
        for (int u = 0; u < 4; ++u) {
            *(uint4*)&sKs[r * RSK + c0 + 8 * u] = *(const uint4*)(gk + 8 * u);
            *(uint4*)&sQs[r * RSK + c0 + 8 * u] = *(const uint4*)(gq + 8 * u);
        }
        if (t < 64) {
            float gl = glog[(bL + l0 + t) * HV + h];
#pragma unroll
            for (int off = 1; off < 64; off <<= 1) {
                float v = __shfl_up(gl, off, 64);
                if (lane >= off) gl += v;
            }
            sG[t]  = gl;
            sEG[t] = __expf(gl);
            sBs[t] = beta[(bL + l0 + t) * HV + h];
        }
    }
    __syncthreads();

    // ---- A = K K^T, Wqk = Q K^T (wave w: cols j in [16w,16w+16)) ----
    {
        ffrag accA[4], accW[4];
#pragma unroll
        for (int mt = 0; mt < 4; ++mt) { accA[mt] = (ffrag)0.f; accW[mt] = (ffrag)0.f; }
#pragma unroll
        for (int kk = 0; kk < 4; ++kk) {
            bfrag bf = *(const bfrag*)&sKs[(16 * w + l16) * RSK + 32 * kk + quad8];
#pragma unroll
            for (int mt = 0; mt < 4; ++mt) {
                bfrag ak = *(const bfrag*)&sKs[(16 * mt + l16) * RSK + 32 * kk + quad8];
                bfrag aq = *(const bfrag*)&sQs[(16 * mt + l16) * RSK + 32 * kk + quad8];
                accA[mt] = __builtin_amdgcn_mfma_f32_16x16x32_bf16(ak, bf, accA[mt], 0, 0, 0);
                accW[mt] = __builtin_amdgcn_mfma_f32_16x16x32_bf16(aq, bf, accW[mt], 0, 0, 0);
            }
        }
        const int j = 16 * w + l16;
        const float gj = sG[j];
        unsigned short* Wqp = Wqkbuf + (size_t)bid * (CHUNK * CHUNK);
#pragma unroll
        for (int mt = 0; mt < 4; ++mt)
#pragma unroll
            for (int reg = 0; reg < 4; ++reg) {
                int i = 16 * mt + quad * 4 + reg;
                float sc = __expf(sG[i] - gj);
                sAf[i * RST + j] = f2bf((j < i) ? sBs[i] * sc * accA[mt][reg] : 0.f);
                Wqp[i * CHUNK + j] = f2bf((j <= i) ? sc * accW[mt][reg] : 0.f);
            }
    }

    // ---- RHS = [ B*V | B*eG*K ] (f32) ----
    {
        const int r  = t >> 2;
        const int c0 = (t & 3) * 32;
        const float be  = sBs[r];
        const float beg = be * sEG[r];
        const unsigned short* gv = qkv + (bL + l0 + r) * CONV_DIM + VOFF + c0;
#pragma unroll
        for (int u = 0; u < 4; ++u) {
            uint4 vv = *(const uint4*)(gv + 8 * u);
            const unsigned short* vp = (const unsigned short*)&vv;
#pragma unroll
            for (int e = 0; e < 8; ++e)
                sRHS[r * RSR1 + c0 + 8 * u + e] = be * bf2f(vp[e]);
        }
#pragma unroll
        for (int u = 0; u < 4; ++u)
#pragma unroll
            for (int e = 0; e < 8; ++e)
                sRHS[r * RSR1 + 128 + c0 + 8 * u + e] =
                    beg * bf2f(sKs[r * RSK + c0 + 8 * u + e]);
    }
    __syncthreads();   // Ks/Qs reads done -> DT overlay writable

    // zero X^T staging (padding rows read by block-solve MFMAs)
    for (int u = t; u < 256 * RSTD / 2; u += 256) ((uint32_t*)sDT)[u] = 0;

    // ---- blocked forward substitution, 256 columns ----
    float* Up = Ubuf + (size_t)bid * (CHUNK * DV);
    for (int sb = 0; sb < 4; ++sb) {
        const int sb16 = 16 * sb;
        if (sb > 0) {
            const int kbn = (sb + 1) >> 1;
            ffrag c16[4];
#pragma unroll
            for (int nt = 0; nt < 4; ++nt) c16[nt] = (ffrag)0.f;
            for (int kb = 0; kb < kbn; ++kb) {
                bfrag af = *(const bfrag*)&sAf[(sb16 + l16) * RST + 32 * kb + quad8];
#pragma unroll
                for (int nt = 0; nt < 4; ++nt) {
                    bfrag bf = *(const bfrag*)&sDT[(64 * w + 16 * nt + l16) * RSTD + 32 * kb + quad8];
                    c16[nt] = __builtin_amdgcn_mfma_f32_16x16x32_bf16(af, bf, c16[nt], 0, 0, 0);
                }
            }
#pragma unroll
            for (int nt = 0; nt < 4; ++nt)
#pragma unroll
                for (int reg = 0; reg < 4; ++reg)
                    sRHS[(sb16 + quad * 4 + reg) * RSR1 + 64 * w + 16 * nt + l16] -= c16[nt][reg];
        }
        __syncthreads();
        {   // serial 16x16 unit-lower solve; thread t owns column t
            const int c = t;
            float d16[16];
#pragma unroll
            for (int e = 0; e < 16; ++e) {
                const int i = sb16 + e;
                float acc = sRHS[i * RSR1 + c];
#pragma unroll
                for (int f = 0; f < 16; ++f)
                    if (f < e) acc -= bf2f(sAf[i * RST + sb16 + f]) * d16[f];
                d16[e] = acc;
            }
#pragma unroll
            for (int e = 0; e < 16; e += 2)
                *(uint32_t*)&sDT[c * RSTD + sb16 + e] = pk2(d16[e], d16[e + 1]);
            if (c < 128) {
                float* up = Up + c;
#pragma unroll
                for (int e = 0; e < 16; ++e) up[(size_t)(sb16 + e) * DV] = d16[e];
            } else {
                unsigned short* wp = qkv + (bL + l0 + sb16) * CONV_DIM + VOFF + (c - 128);
#pragma unroll
                for (int e = 0; e < 16; ++e) wp[(size_t)e * CONV_DIM] = f2bf(-d16[e]);
            }
        }
        __syncthreads();
    }
}

// ---- pass-2 LDS layout ----
constexpr int P2_oSTb = 0;                         // 128*136*2 = 34816
constexpr int P2_oWk  = P2_oSTb + 128 * RSK * 2;   // 34816 (+17408)
constexpr int P2_oQs  = P2_oWk + 64 * RSK * 2;     // 52224 (+17408)
constexpr int P2_oKT  = P2_oQs + 64 * RSK * 2;     // 69632 (+18432)
constexpr int P2_oWqk = P2_oKT + 128 * RST * 2;    // 88064 (+9216)
constexpr int P2_oDT  = P2_oWqk + 64 * RST * 2;    // 97280 (+18432)
constexpr int P2_oDdT = P2_oDT + 128 * RST * 2;    // 115712 (+18432) -> 134144
constexpr int P2_oU   = P2_oDT;                    // overlay DT+DdT (64*132*4 = 33792 <= 36864)
constexpr int P2_oEG  = P2_oDdT + 128 * RST * 2;   // 134144
constexpr int P2_oEGd = P2_oEG + 256;              // 134400
constexpr int P2_oNW  = P2_oEGd + 256;             // 134656
constexpr int P2_SMEM = P2_oNW + 512;              // 135168

__global__ __launch_bounds__(256, 1) void chunk_scan2(
    const unsigned short* __restrict__ qkv,   // q,k raw; v-slot holds Wkn
    const float* __restrict__ glog,
    const float* __restrict__ Ubuf,
    const unsigned short* __restrict__ Wqkbuf,
    unsigned short* __restrict__ z_io,
    const float* __restrict__ norm_w)
{
    extern __shared__ __align__(16) char smem[];
    unsigned short* sSTb = (unsigned short*)(smem + P2_oSTb);
    unsigned short* sWk  = (unsigned short*)(smem + P2_oWk);
    unsigned short* sQs  = (unsigned short*)(smem + P2_oQs);
    unsigned short* sKT  = (unsigned short*)(smem + P2_oKT);
    unsigned short* sWqk = (unsigned short*)(smem + P2_oWqk);
    unsigned short* sDT  = (unsigned short*)(smem + P2_oDT);
    unsigned short* sDdT = (unsigned short*)(smem + P2_oDdT);
    float* sU   = (float*)(smem + P2_oU);
    float* sEG  = (float*)(smem + P2_oEG);
    float* sEGd = (float*)(smem + P2_oEGd);
    float* sNW  = (float*)(smem + P2_oNW);

    const int bb = blockIdx.x >> 5;
    const int h  = blockIdx.x & (HV - 1);
    const int hk = h >> 1;
    const int t    = threadIdx.x;
    const int w    = t >> 6;
    const int lane = t & 63;
    const int quad = lane >> 4;
    const int l16  = lane & 15;
    const int quad8 = quad * 8;
    const size_t bL = (size_t)bb * L;
    const int VOFF = 2 * KEY_DIM + h * DV;
    const size_t chbase0 = ((size_t)bb * HV + h) * NCHUNK;

    // persistent state: ST[dv][dk], wave w owns dv in [32w,32w+32)
    ffrag accS[2][8];
#pragma unroll
    for (int mt = 0; mt < 2; ++mt)
#pragma unroll
        for (int nt = 0; nt < 8; ++nt) accS[mt][nt] = (ffrag)0.f;

    for (int u = t; u < 64 * RSK; u += 256) ((uint32_t*)sSTb)[u] = 0;  // 128*136 bf16
    if (t < 128) sNW[t] = norm_w[t];

    for (int ch = 0; ch < NCHUNK; ++ch) {
        const int l0 = ch * CHUNK;
        const size_t cb = chbase0 + ch;
        __syncthreads();   // A: prev STb written; all prev-phase LDS reads done

        // ---- load phase ----
        {
            const int r  = t >> 2;
            const int c0 = (t & 3) * 32;
            const unsigned short* grow = qkv + (bL + l0 + r) * CONV_DIM;
            const unsigned short* gq = grow + hk * DK + c0;
            const unsigned short* gk = grow + KEY_DIM + hk * DK + c0;
            const unsigned short* gw = grow + VOFF + c0;
#pragma unroll
            for (int u = 0; u < 4; ++u) {
                uint4 kv = *(const uint4*)(gk + 8 * u);
                *(uint4*)&sQs[r * RSK + c0 + 8 * u] = *(const uint4*)(gq + 8 * u);
                *(uint4*)&sWk[r * RSK + c0 + 8 * u] = *(const uint4*)(gw + 8 * u);
                const unsigned short* kp = (const unsigned short*)&kv;
#pragma unroll
                for (int e = 0; e < 8; ++e)
                    sKT[(c0 + 8 * u + e) * RST + r] = kp[e];
            }
            const float* up = Ubuf + cb * (CHUNK * DV) + r * DV + c0;
#pragma unroll
            for (int u = 0; u < 8; ++u)
                *(float4*)&sU[r * RSR2 + c0 + 4 * u] = *(const float4*)(up + 4 * u);
            const int cw = (t & 3) * 16;
            const unsigned short* qp = Wqkbuf + cb * (CHUNK * CHUNK) + r * CHUNK + cw;
#pragma unroll
            for (int u = 0; u < 2; ++u)
                *(uint4*)&sWqk[r * RST + cw + 8 * u] = *(const uint4*)(qp + 8 * u);
            if (t < 64) {
                float gl = glog[(bL + l0 + t) * HV + h];
#pragma unroll
                for (int off = 1; off < 64; off <<= 1) {
                    float v = __shfl_up(gl, off, 64);
                    if (lane >= off) gl += v;
                }
                float gc = __shfl(gl, 63, 64);
                sEG[t]  = __expf(gl);
                sEGd[t] = __expf(gc - gl);
            }
        }
        __syncthreads();   // B

        // ---- Delta = U + Wkn . ST (wave w: dv in [32w,32w+32)) ----
        ffrag accD[4][2];
#pragma unroll
        for (int mt = 0; mt < 4; ++mt)
#pragma unroll
            for (int nt = 0; nt < 2; ++nt)
#pragma unroll
                for (int reg = 0; reg < 4; ++reg)
                    accD[mt][nt][reg] =
                        sU[(16 * mt + quad * 4 + reg) * RSR2 + 32 * w + 16 * nt + l16];
#pragma unroll
        for (int kk = 0; kk < 4; ++kk) {
            bfrag b0 = *(const bfrag*)&sSTb[(32 * w + l16) * RSK + 32 * kk + quad8];
            bfrag b1 = *(const bfrag*)&sSTb[(32 * w + 16 + l16) * RSK + 32 * kk + quad8];
#pragma unroll
            for (int mt = 0; mt < 4; ++mt) {
                bfrag af = *(const bfrag*)&sWk[(16 * mt + l16) * RSK + 32 * kk + quad8];
                accD[mt][0] = __builtin_amdgcn_mfma_f32_16x16x32_bf16(af, b0, accD[mt][0], 0, 0, 0);
                accD[mt][1] = __builtin_amdgcn_mfma_f32_16x16x32_bf16(af, b1, accD[mt][1], 0, 0, 0);
            }
        }
        __syncthreads();   // C: sU reads done -> DT/DdT overlay writable

        // ---- write Delta^T and decayed Delta^T ----
#pragma unroll
        for (int mt = 0; mt < 4; ++mt)
#pragma unroll
            for (int nt = 0; nt < 2; ++nt) {
                const int dv = 32 * w + 16 * nt + l16;
#pragma unroll
                for (int reg = 0; reg < 4; ++reg) {
                    const int i = 16 * mt + quad * 4 + reg;
                    float d = accD[mt][nt][reg];
                    sDT[dv * RST + i]  = f2bf(d);
                    sDdT[dv * RST + i] = f2bf(d * sEGd[i]);
                }
            }
        __syncthreads();   // D

        // ---- O = eG*(Q ST) + Wqk . Delta ; epilogue ; state update ----
        {
            ffrag accO[8];
#pragma unroll
            for (int nt = 0; nt < 8; ++nt) accO[nt] = (ffrag)0.f;
#pragma unroll
            for (int kk = 0; kk < 4; ++kk) {
                bfrag af = *(const bfrag*)&sQs[(16 * w + l16) * RSK + 32 * kk + quad8];
#pragma unroll
                for (int nt = 0; nt < 8; ++nt) {
                    bfrag bf = *(const bfrag*)&sSTb[(16 * nt + l16) * RSK + 32 * kk + quad8];
                    accO[nt] = __builtin_amdgcn_mfma_f32_16x16x32_bf16(af, bf, accO[nt], 0, 0, 0);
                }
            }
#pragma unroll
            for (int nt = 0; nt < 8; ++nt)
#pragma unroll
                for (int reg = 0; reg < 4; ++reg)
                    accO[nt][reg] *= sEG[16 * w + quad * 4 + reg];
#pragma unroll
            for (int kk = 0; kk < 2; ++kk) {
                bfrag af = *(const bfrag*)&sWqk[(16 * w + l16) * RST + 32 * kk + quad8];
#pragma unroll
                for (int nt = 0; nt < 8; ++nt) {
                    bfrag bf = *(const bfrag*)&sDT[(16 * nt + l16) * RST + 32 * kk + quad8];
                    accO[nt] = __builtin_amdgcn_mfma_f32_16x16x32_bf16(af, bf, accO[nt], 0, 0, 0);
                }
            }
            // RMSNorm over dv + silu(z) gate, write y over z
            float inv[4];
#pragma unroll
            for (int reg = 0; reg < 4; ++reg) {
                float p = 0.f;
#pragma unroll
                for (int nt = 0; nt < 8; ++nt) p += accO[nt][reg] * accO[nt][reg];
#pragma unroll
                for (int m = 1; m < 16; m <<= 1) p += __shfl_xor(p, m, 64);
                inv[reg] = rsqrtf(p * (1.f / 128.f) + EPS);
            }
            const int i0 = 16 * w + quad * 4;
#pragma unroll
            for (int nt = 0; nt < 8; ++nt) {
                const int dv = 16 * nt + l16;
                const float nwv = sNW[dv];
#pragma unroll
                for (int reg = 0; reg < 4; ++reg) {
                    size_t zi = (bL + l0 + i0 + reg) * (size_t)VAL_DIM + h * DV + dv;
                    float zv = bf2f(z_io[zi]);
                    float y = accO[nt][reg] * inv[reg] * nwv * (zv / (1.f + __expf(-zv)));
                    z_io[zi] = f2bf(y);
                }
            }

            // state update: ST = eGc*ST + DdT . KT
            const float eGc = sEG[63];
#pragma unroll
            for (int mt = 0; mt < 2; ++mt)
#pragma unroll
                for (int nt = 0; nt < 8; ++nt)
#pragma unroll
                    for (int reg = 0; reg < 4; ++reg) accS[mt][nt][reg] *= eGc;
#pragma unroll
            for (int kk = 0; kk < 2; ++kk) {
                bfrag a0 = *(const bfrag*)&sDdT[(32 * w + l16) * RST + 32 * kk + quad8];
                bfrag a1 = *(const bfrag*)&sDdT[(32 * w + 16 + l16) * RST + 32 * kk + quad8];
#pragma unroll
                for (int nt = 0; nt < 8; ++nt) {
                    bfrag bk = *(const bfrag*)&sKT[(16 * nt + l16) * RST + 32 * kk + quad8];
                    accS[0][nt] = __builtin_amdgcn_mfma_f32_16x16x32_bf16(a0, bk, accS[0][nt], 0, 0, 0);
                    accS[1][nt] = __builtin_amdgcn_mfma_f32_16x16x32_bf16(a1, bk, accS[1][nt], 0, 0, 0);
                }
            }
        }
        __syncthreads();   // E: all STb/DT/DdT/KT reads done

        // ---- materialize STb (bf16) for next chunk ----
#pragma unroll
        for (int mt = 0; mt < 2; ++mt)
#pragma unroll
            for (int nt = 0; nt < 8; ++nt)
#pragma unroll
                for (int reg = 0; reg < 4; ++reg)
                    sSTb[(32 * w + 16 * mt + quad * 4 + reg) * RSK + 16 * nt + l16] =
                        f2bf(accS[mt][nt][reg]);
    }
}

// ---------------- launch ----------------
extern "C" void kernel_launch(void* const* d_in, const int* in_sizes, int n_in,
                              void* d_out, int out_size, void* d_ws, size_t ws_size,
                              hipStream_t stream)
{
    const float* x        = (const float*)d_in[0];
    const float* W_qkv    = (const float*)d_in[1];
    const float* W_z      = (const float*)d_in[2];
    const float* W_a      = (const float*)d_in[3];
    const float* W_b      = (const float*)d_in[4];
    const float* conv_w   = (const float*)d_in[5];
    const float* A_log    = (const float*)d_in[6];
    const float* dt_bias  = (const float*)d_in[7];
    const float* norm_w   = (const float*)d_in[8];
    const float* W_out    = (const float*)d_in[9];
    float* out = (float*)d_out;
    char*  ws  = (char*)d_ws;

    if (ws_size < WS_NEED_BYTES) return;

    unsigned short* qkv = (unsigned short*)(ws + OFF_QKV);
    unsigned short* z   = (unsigned short*)(ws + OFF_Z);
    float* a    = (float*)(ws + OFF_A);
    float* bbuf = (float*)(ws + OFF_B);
    float* gl   = (float*)(ws + OFF_G);
    float* beta = (float*)(ws + OFF_BETA);
    float* Ubuf = (float*)(ws + OFF_U);
    unsigned short* Wqkbuf = (unsigned short*)(ws + OFF_WQK);

    static bool attr_set = false;
    if (!attr_set) {
        (void)hipFuncSetAttribute((const void*)chunk_prep,
                                  hipFuncAttributeMaxDynamicSharedMemorySize, P1_SMEM);
        (void)hipFuncSetAttribute((const void*)chunk_scan2,
                                  hipFuncAttributeMaxDynamicSharedMemorySize, P2_SMEM);
        attr_set = true;
    }

    // 1. fused input projections (MFMA bf16)
    dim3 g1((NPROJ + 127) / 128, ROWS / 128);
    gemm_inproj<<<g1, 256, 0, stream>>>(x, W_qkv, W_z, W_a, W_b, qkv, z, a, bbuf);
    // 2. depthwise causal conv + silu
    conv_silu<<<(B * CONV_DIM) / 256, 256, 0, stream>>>(qkv, conv_w);
    // 3. l2norm q,k heads
    normqk<<<(B * L * 2 * HK) / 4, 256, 0, stream>>>(qkv);
    // 4. gate coefficients (log-space g)
    gatecoef<<<(B * L * HV) / 256, 256, 0, stream>>>(a, bbuf, A_log, dt_bias, gl, beta);
    // 5a. parallel chunk prep: A, Wqk, solve -> U (f32), Wkn (over v-slot)
    chunk_prep<<<NCH_TOT, 256, P1_SMEM, stream>>>(qkv, gl, beta, Ubuf, Wqkbuf);
    // 5b. sequential scan: Delta/O/state + fused gated RMSNorm (y overwrites z)
    chunk_scan2<<<B * HV, 256, P2_SMEM, stream>>>(qkv, gl, Ubuf, Wqkbuf, z, norm_w);
    // 6. output projection (MFMA bf16)
    dim3 g2(DIM / 128, ROWS / 128);
    gemm_outproj<<<g2, 256, 0, stream>>>(z, W_out, out);
}

// Round 2
// 1108.386 us; speedup vs baseline: 1.6977x; 1.3213x over previous
//
#include <hip/hip_runtime.h>
#include <hip/hip_bf16.h>
#include <cstddef>
#include <cstdint>

// ---------------- problem constants ----------------
constexpr int B = 2, L = 2048, DIM = 2048;
constexpr int HK = 16, HV = 32, DK = 128, DV = 128;
constexpr int KEY_DIM = HK * DK;                    // 2048
constexpr int VAL_DIM = HV * DV;                    // 4096
constexpr int CONV_DIM = 2 * KEY_DIM + VAL_DIM;     // 8192
constexpr int NPROJ = CONV_DIM + VAL_DIM + HV + HV; // 12352
constexpr int NPAD  = ((NPROJ + 127) / 128) * 128;  // 12416
constexpr size_t ROWS = (size_t)B * L;              // 4096
constexpr float EPS = 1e-6f;
constexpr int CHUNK = 64, NCHUNK = L / CHUNK;       // 32 chunks
constexpr int NCH_TOT = B * HV * NCHUNK;            // 2048 chunk-head blocks

// workspace layout (BYTE offsets). Total ~187 MB (bf16 staging overlaid).
constexpr size_t OFF_QKV  = 0;                                   // bf16
constexpr size_t OFF_Z    = OFF_QKV + ROWS * CONV_DIM * 2;       // bf16 (y in-place)
constexpr size_t OFF_A    = OFF_Z   + ROWS * VAL_DIM * 2;        // f32
constexpr size_t OFF_B    = OFF_A   + ROWS * HV * 4;
constexpr size_t OFF_G    = OFF_B   + ROWS * HV * 4;             // g (log-space)
constexpr size_t OFF_BETA = OFF_G   + ROWS * HV * 4;
constexpr size_t OFF_U    = OFF_BETA + ROWS * HV * 4;            // f32 U = T(BV)
constexpr size_t OFF_WQK  = OFF_U + (size_t)NCH_TOT * CHUNK * DV * 4;  // bf16 Wqk
constexpr size_t WS_NEED_BYTES = OFF_WQK + (size_t)NCH_TOT * CHUNK * CHUNK * 2;
// overlays (lifetime-disjoint):
//   Wcat bf16 (NPAD x DIM, 50.9MB)  @ OFF_U    (dead once gemm_inproj done; U written later)
//   x    bf16 (ROWS x DIM, 16.8MB)  @ OFF_WQK  (dead once gemm_inproj done; Wqk written later)
//   Wout bf16 (DIM x VAL_DIM,16.8MB)@ OFF_U    (written after chunk_scan2, U dead by then)
constexpr size_t OFF_WCAT = OFF_U;
constexpr size_t OFF_XB   = OFF_WQK;
constexpr size_t OFF_WOB  = OFF_U;

// ---------------- bf16 helpers ----------------
__device__ __forceinline__ float bf2f(unsigned short u) {
    union { float f; uint32_t i; } c; c.i = ((uint32_t)u) << 16; return c.f;
}
__device__ __forceinline__ unsigned short f2bf(float f) {
    union { float f; uint32_t u; } c; c.f = f;
    uint32_t u = c.u + 0x7FFFu + ((c.u >> 16) & 1u);   // RTNE
    return (unsigned short)(u >> 16);
}
__device__ __forceinline__ uint32_t pk2(float a, float b) {
    return (uint32_t)f2bf(a) | ((uint32_t)f2bf(b) << 16);
}

// MFMA fragment types (16x16x32 bf16)
typedef __attribute__((ext_vector_type(8))) short bfrag;   // 8 bf16
typedef __attribute__((ext_vector_type(4))) float ffrag;   // 4 f32

// async global->LDS, 16B per lane (dest must be wave-uniform base; lane*16 implied)
__device__ __forceinline__ void gload16(const unsigned short* g, unsigned short* l) {
    __builtin_amdgcn_global_load_lds(
        (const __attribute__((address_space(1))) uint32_t*)g,
        (__attribute__((address_space(3))) uint32_t*)l, 16, 0, 0);
}

// ================= f32 -> bf16 conversion kernels =================
__device__ __forceinline__ const float* w_row_multi(int n, const float* Wq, const float* Wz,
                                                    const float* Wa, const float* Wb) {
    if (n < CONV_DIM)                return Wq + (size_t)n * DIM;
    if (n < CONV_DIM + VAL_DIM)      return Wz + (size_t)(n - CONV_DIM) * DIM;
    if (n < CONV_DIM + VAL_DIM + HV) return Wa + (size_t)(n - CONV_DIM - VAL_DIM) * DIM;
    return Wb + (size_t)(n - CONV_DIM - VAL_DIM - HV) * DIM;
}

__global__ __launch_bounds__(256) void cvt_wcat(
    const float* __restrict__ Wq, const float* __restrict__ Wz,
    const float* __restrict__ Wa, const float* __restrict__ Wb,
    unsigned short* __restrict__ dst)
{
    const int r = blockIdx.x;            // 0..NPAD-1
    const int c = threadIdx.x * 8;       // 256*8 = 2048 = DIM
    uint4 o;
    if (r < NPROJ) {
        const float* s = w_row_multi(r, Wq, Wz, Wa, Wb) + c;
        float4 v0 = *(const float4*)s;
        float4 v1 = *(const float4*)(s + 4);
        o = make_uint4(pk2(v0.x, v0.y), pk2(v0.z, v0.w), pk2(v1.x, v1.y), pk2(v1.z, v1.w));
    } else {
        o = make_uint4(0u, 0u, 0u, 0u);
    }
    *(uint4*)&dst[(size_t)r * DIM + c] = o;
}

__global__ __launch_bounds__(256) void cvt_f32bf(const float* __restrict__ src,
                                                 unsigned short* __restrict__ dst, int cols)
{
    const size_t r = blockIdx.x;
    for (int c = threadIdx.x * 8; c < cols; c += 256 * 8) {
        const float* s = src + r * cols + c;
        float4 v0 = *(const float4*)s;
        float4 v1 = *(const float4*)(s + 4);
        *(uint4*)&dst[r * cols + c] =
            make_uint4(pk2(v0.x, v0.y), pk2(v0.z, v0.w), pk2(v1.x, v1.y), pk2(v1.z, v1.w));
    }
}

// ================= shared GEMM epilogue helper (inproj) =================
__device__ __forceinline__ void store_multi(int m, int n, float v,
                                            unsigned short* qkv, unsigned short* z,
                                            float* a, float* b) {
    if (n < CONV_DIM) {
        qkv[(size_t)m * CONV_DIM + n] = f2bf(v);
    } else if (n < CONV_DIM + VAL_DIM) {
        z[(size_t)m * VAL_DIM + (n - CONV_DIM)] = f2bf(v);
    } else if (n < CONV_DIM + VAL_DIM + HV) {
        a[(size_t)m * HV + (n - CONV_DIM - VAL_DIM)] = v;
    } else if (n < NPROJ) {
        b[(size_t)m * HV + (n - CONV_DIM - VAL_DIM - HV)] = v;
    }
}

// ===================================================================
// m97-style bf16 GEMM: C(128x128 tile) = A(rowmajor K) . B(rowmajor K)^T
// BK=64, global_load_lds width 16, linear LDS + XOR slot swizzle
// (source pre-swizzled, read swizzled: slot ^= row&7 -> ~conflict-free).
// ===================================================================
constexpr int BK = 64;

// ---- fused input projection GEMM (bf16 x, bf16 Wcat) ----
__global__ __launch_bounds__(256) void gemm_inproj_bf(
    const unsigned short* __restrict__ xb,     // (ROWS, DIM)
    const unsigned short* __restrict__ Wcat,   // (NPAD, DIM), pad rows zero
    unsigned short* __restrict__ qkv, unsigned short* __restrict__ z,
    float* __restrict__ a_out, float* __restrict__ b_out)
{
    __shared__ __align__(16) unsigned short As[128 * BK];
    __shared__ __align__(16) unsigned short Bs[128 * BK];

    // XCD-aware bijective swizzle; col-major decomposition so each XCD
    // streams a column panel of Wcat through its private L2.
    constexpr int NBX = NPAD / 128;            // 97
    constexpr int NB  = NBX * 32;              // 3104 (divisible by 8)
    const int id  = blockIdx.x;
    const int swz = (id & 7) * (NB >> 3) + (id >> 3);
    const int bx  = swz >> 5;                  // 0..96
    const int by  = swz & 31;                  // 0..31
    const int row0 = by * 128;
    const int col0 = bx * 128;

    const int t = threadIdx.x, lane = t & 63, wid = t >> 6;
    const int quad = lane >> 4, l16 = lane & 15;
    const int wm = (wid >> 1) * 64, wn = (wid & 1) * 64;
    const int srow = lane >> 3, sslot = lane & 7;
    const int sw8 = ((sslot ^ srow) * 8);      // pre-swizzled source slot

    ffrag acc[4][4];
#pragma unroll
    for (int i = 0; i < 4; ++i)
#pragma unroll
        for (int j = 0; j < 4; ++j) acc[i][j] = (ffrag)0.f;

    const unsigned short* aS = xb   + (size_t)(row0 + wid * 8 + srow) * DIM + sw8;
    const unsigned short* bS = Wcat + (size_t)(col0 + wid * 8 + srow) * DIM + sw8;
    unsigned short* aD = As + (wid * 8) * BK;
    unsigned short* bD = Bs + (wid * 8) * BK;

    const int aBase = (wm + l16) * BK;
    const int bBase = (wn + l16) * BK;
    const int x7 = l16 & 7;

    for (int k0 = 0; k0 < DIM; k0 += BK) {
        __syncthreads();                       // prev reads done
#pragma unroll
        for (int c = 0; c < 4; ++c) {
            gload16(aS + (size_t)(c * 32) * DIM + k0, aD + c * 32 * BK);
            gload16(bS + (size_t)(c * 32) * DIM + k0, bD + c * 32 * BK);
        }
        __syncthreads();                       // drains vmcnt before use
#pragma unroll
        for (int kk = 0; kk < 2; ++kk) {
            const int so = ((kk * 4 + quad) ^ x7) * 8;
            bfrag aF[4], bF[4];
#pragma unroll
            for (int mt = 0; mt < 4; ++mt) aF[mt] = *(const bfrag*)&As[aBase + mt * 16 * BK + so];
#pragma unroll
            for (int nt = 0; nt < 4; ++nt) bF[nt] = *(const bfrag*)&Bs[bBase + nt * 16 * BK + so];
#pragma unroll
            for (int mt = 0; mt < 4; ++mt)
#pragma unroll
                for (int nt = 0; nt < 4; ++nt)
                    acc[mt][nt] = __builtin_amdgcn_mfma_f32_16x16x32_bf16(
                        aF[mt], bF[nt], acc[mt][nt], 0, 0, 0);
        }
    }

#pragma unroll
    for (int mt = 0; mt < 4; ++mt)
#pragma unroll
        for (int nt = 0; nt < 4; ++nt) {
            int gr = row0 + wm + mt * 16 + quad * 4;
            int gc = col0 + wn + nt * 16 + l16;
#pragma unroll
            for (int reg = 0; reg < 4; ++reg)
                store_multi(gr + reg, gc, acc[mt][nt][reg], qkv, z, a_out, b_out);
        }
}

// ---- output projection GEMM (bf16 y, bf16 W_out) ----
__global__ __launch_bounds__(256) void gemm_outproj_bf(
    const unsigned short* __restrict__ A,    // (ROWS, VAL_DIM)
    const unsigned short* __restrict__ Wb,   // (DIM, VAL_DIM)
    float* __restrict__ C)                   // (ROWS, DIM)
{
    __shared__ __align__(16) unsigned short As[128 * BK];
    __shared__ __align__(16) unsigned short Bs[128 * BK];

    constexpr int NB = (DIM / 128) * 32;       // 512
    const int id  = blockIdx.x;
    const int swz = (id & 7) * (NB >> 3) + (id >> 3);
    const int bx  = swz >> 5;
    const int by  = swz & 31;
    const int row0 = by * 128;
    const int col0 = bx * 128;

    const int t = threadIdx.x, lane = t & 63, wid = t >> 6;
    const int quad = lane >> 4, l16 = lane & 15;
    const int wm = (wid >> 1) * 64, wn = (wid & 1) * 64;
    const int srow = lane >> 3, sslot = lane & 7;
    const int sw8 = ((sslot ^ srow) * 8);

    ffrag acc[4][4];
#pragma unroll
    for (int i = 0; i < 4; ++i)
#pragma unroll
        for (int j = 0; j < 4; ++j) acc[i][j] = (ffrag)0.f;

    const unsigned short* aS = A  + (size_t)(row0 + wid * 8 + srow) * VAL_DIM + sw8;
    const unsigned short* bS = Wb + (size_t)(col0 + wid * 8 + srow) * VAL_DIM + sw8;
    unsigned short* aD = As + (wid * 8) * BK;
    unsigned short* bD = Bs + (wid * 8) * BK;

    const int aBase = (wm + l16) * BK;
    const int bBase = (wn + l16) * BK;
    const int x7 = l16 & 7;

    for (int k0 = 0; k0 < VAL_DIM; k0 += BK) {
        __syncthreads();
#pragma unroll
        for (int c = 0; c < 4; ++c) {
            gload16(aS + (size_t)(c * 32) * VAL_DIM + k0, aD + c * 32 * BK);
            gload16(bS + (size_t)(c * 32) * VAL_DIM + k0, bD + c * 32 * BK);
        }
        __syncthreads();
#pragma unroll
        for (int kk = 0; kk < 2; ++kk) {
            const int so = ((kk * 4 + quad) ^ x7) * 8;
            bfrag aF[4], bF[4];
#pragma unroll
            for (int mt = 0; mt < 4; ++mt) aF[mt] = *(const bfrag*)&As[aBase + mt * 16 * BK + so];
#pragma unroll
            for (int nt = 0; nt < 4; ++nt) bF[nt] = *(const bfrag*)&Bs[bBase + nt * 16 * BK + so];
#pragma unroll
            for (int mt = 0; mt < 4; ++mt)
#pragma unroll
                for (int nt = 0; nt < 4; ++nt)
                    acc[mt][nt] = __builtin_amdgcn_mfma_f32_16x16x32_bf16(
                        aF[mt], bF[nt], acc[mt][nt], 0, 0, 0);
        }
    }

#pragma unroll
    for (int mt = 0; mt < 4; ++mt)
#pragma unroll
        for (int nt = 0; nt < 4; ++nt) {
            int gr = row0 + wm + mt * 16 + quad * 4;
            int gc = col0 + wn + nt * 16 + l16;
#pragma unroll
            for (int reg = 0; reg < 4; ++reg)
                C[(size_t)(gr + reg) * DIM + gc] = acc[mt][nt][reg];
        }
}

// ================= depthwise causal conv1d + SiLU =================
__global__ __launch_bounds__(256) void conv_silu(unsigned short* __restrict__ qkv,
                                                 const float* __restrict__ conv_w)
{
    int idx = blockIdx.x * blockDim.x + threadIdx.x;
    int b = idx >> 13;
    int c = idx & (CONV_DIM - 1);
    const float w0 = conv_w[c * 4 + 0];
    const float w1 = conv_w[c * 4 + 1];
    const float w2 = conv_w[c * 4 + 2];
    const float w3 = conv_w[c * 4 + 3];
    unsigned short* p = qkv + (size_t)b * L * CONV_DIM + c;
    float x0 = 0.f, x1 = 0.f, x2 = 0.f;
    for (int l0 = 0; l0 < L; l0 += 8) {
        float xv[8];
#pragma unroll
        for (int j = 0; j < 8; ++j) xv[j] = bf2f(p[(size_t)(l0 + j) * CONV_DIM]);
#pragma unroll
        for (int j = 0; j < 8; ++j) {
            float h = w0 * x0 + w1 * x1 + w2 * x2 + w3 * xv[j];
            float s = h / (1.f + __expf(-h));
            p[(size_t)(l0 + j) * CONV_DIM] = f2bf(s);
            x0 = x1; x1 = x2; x2 = xv[j];
        }
    }
}

// ================= l2norm of q,k heads =================
__global__ __launch_bounds__(256) void normqk(unsigned short* __restrict__ qkv)
{
    int wid  = blockIdx.x * 4 + (threadIdx.x >> 6);
    int lane = threadIdx.x & 63;
    int hk  = wid & 15;
    int sel = (wid >> 4) & 1;
    int row = wid >> 5;
    unsigned short* p = qkv + (size_t)row * CONV_DIM + sel * KEY_DIM + hk * DK;
    float x0 = bf2f(p[lane]), x1 = bf2f(p[lane + 64]);
    float ss = x0 * x0 + x1 * x1;
#pragma unroll
    for (int o = 32; o >= 1; o >>= 1) ss += __shfl_xor(ss, o);
    float sc = rsqrtf(ss + 1e-6f);
    if (sel == 0) sc *= 0.08838834764831845f;   // DK^-0.5
    p[lane]      = f2bf(x0 * sc);
    p[lane + 64] = f2bf(x1 * sc);
}

// ================= gate coefficients: g (log) and beta =================
__global__ __launch_bounds__(256) void gatecoef(const float* __restrict__ a_buf,
                                                const float* __restrict__ b_buf,
                                                const float* __restrict__ A_log,
                                                const float* __restrict__ dt_bias,
                                                float* __restrict__ glog,
                                                float* __restrict__ beta)
{
    int idx = blockIdx.x * blockDim.x + threadIdx.x;
    int h = idx & (HV - 1);
    float av = a_buf[idx];
    float bv = b_buf[idx];
    float x  = av + dt_bias[h];
    float sp = (x > 20.f) ? x : log1pf(__expf(x));
    glog[idx] = -__expf(A_log[h]) * sp;
    beta[idx] = 1.f / (1.f + __expf(-bv));
}

// ===================================================================
// Two-pass chunked gated delta rule (unchanged from round 1).
// ===================================================================

// shared strides
constexpr int RSK  = 136;   // 128-wide bf16 rows (128 data + 8 pad)
constexpr int RST  = 72;    // 64-wide bf16 rows (64 data + 8 pad)
constexpr int RSTD = 68;    // pass-1 X^T rows (64 data + 4 pad)
constexpr int RSR1 = 260;   // pass-1 RHS f32 rows (256 data + 4 pad)
constexpr int RSR2 = 132;   // pass-2 U f32 rows (128 data + 4 pad)

// ---- pass-1 LDS layout ----
constexpr int P1_oKs  = 0;                       // 64*136*2 = 17408
constexpr int P1_oQs  = P1_oKs + 64 * RSK * 2;   // 17408
constexpr int P1_oDT  = 0;                       // overlay Ks+Qs: 256*68*2 = 34816
constexpr int P1_oAf  = P1_oQs + 64 * RSK * 2;   // 34816 (64*72*2 = 9216)
constexpr int P1_oRHS = P1_oAf + 64 * RST * 2;   // 44032 (64*260*4 = 66560)
constexpr int P1_oG   = P1_oRHS + 64 * RSR1 * 4; // 110592
constexpr int P1_oEG  = P1_oG + 256;
constexpr int P1_oBs  = P1_oEG + 256;
constexpr int P1_SMEM = P1_oBs + 256;            // 111616

__global__ __launch_bounds__(256, 1) void chunk_prep(
    unsigned short* __restrict__ qkv,     // v-slot overwritten with Wkn
    const float* __restrict__ glog,
    const float* __restrict__ beta,
    float* __restrict__ Ubuf,
    unsigned short* __restrict__ Wqkbuf)
{
    extern __shared__ __align__(16) char smem[];
    unsigned short* sKs = (unsigned short*)(smem + P1_oKs);
    unsigned short* sQs = (unsigned short*)(smem + P1_oQs);
    unsigned short* sDT = (unsigned short*)(smem + P1_oDT);
    unsigned short* sAf = (unsigned short*)(smem + P1_oAf);
    float* sRHS = (float*)(smem + P1_oRHS);
    float* sG   = (float*)(smem + P1_oG);
    float* sEG  = (float*)(smem + P1_oEG);
    float* sBs  = (float*)(smem + P1_oBs);

    const int bid = blockIdx.x;
    const int ch = bid & (NCHUNK - 1);
    const int h  = (bid >> 5) & (HV - 1);
    const int bb = bid >> 10;
    const int hk = h >> 1;
    const int t    = threadIdx.x;
    const int w    = t >> 6;
    const int lane = t & 63;
    const int quad = lane >> 4;
    const int l16  = lane & 15;
    const int quad8 = quad * 8;
    const size_t bL = (size_t)bb * L;
    const int l0 = ch * CHUNK;
    const int VOFF = 2 * KEY_DIM + h * DV;

    // ---- loads ----
    {
        const int r  = t >> 2;
        const int c0 = (t & 3) * 32;
        const unsigned short* grow = qkv + (bL + l0 + r) * CONV_DIM;
        const unsigned short* gq = grow + hk * DK + c0;
        const unsigned short* gk = grow + KEY_DIM + hk * DK + c0;
#pragma unroll
        for (int u = 0; u < 4; ++u) {
            *(uint4*)&sKs[r * RSK + c0 + 8 * u] = *(const uint4*)(gk + 8 * u);
            *(uint4*)&sQs[r * RSK + c0 + 8 * u] = *(const uint4*)(gq + 8 * u);
        }
        if (t < 64) {
            float gl = glog[(bL + l0 + t) * HV + h];
#pragma unroll
            for (int off = 1; off < 64; off <<= 1) {
                float v = __shfl_up(gl, off, 64);
                if (lane >= off) gl += v;
            }
            sG[t]  = gl;
            sEG[t] = __expf(gl);
            sBs[t] = beta[(bL + l0 + t) * HV + h];
        }
    }
    __syncthreads();

    // ---- A = K K^T, Wqk = Q K^T (wave w: cols j in [16w,16w+16)) ----
    {
        ffrag accA[4], accW[4];
#pragma unroll
        for (int mt = 0; mt < 4; ++mt) { accA[mt] = (ffrag)0.f; accW[mt] = (ffrag)0.f; }
#pragma unroll
        for (int kk = 0; kk < 4; ++kk) {
            bfrag bf = *(const bfrag*)&sKs[(16 * w + l16) * RSK + 32 * kk + quad8];
#pragma unroll
            for (int mt = 0; mt < 4; ++mt) {
                bfrag ak = *(const bfrag*)&sKs[(16 * mt + l16) * RSK + 32 * kk + quad8];
                bfrag aq = *(const bfrag*)&sQs[(16 * mt + l16) * RSK + 32 * kk + quad8];
                accA[mt] = __builtin_amdgcn_mfma_f32_16x16x32_bf16(ak, bf, accA[mt], 0, 0, 0);
                accW[mt] = __builtin_amdgcn_mfma_f32_16x16x32_bf16(aq, bf, accW[mt], 0, 0, 0);
            }
        }
        const int j = 16 * w + l16;
        const float gj = sG[j];
        unsigned short* Wqp = Wqkbuf + (size_t)bid * (CHUNK * CHUNK);
#pragma unroll
        for (int mt = 0; mt < 4; ++mt)
#pragma unroll
            for (int reg = 0; reg < 4; ++reg) {
                int i = 16 * mt + quad * 4 + reg;
                float sc = __expf(sG[i] - gj);
                sAf[i * RST + j] = f2bf((j < i) ? sBs[i] * sc * accA[mt][reg] : 0.f);
                Wqp[i * CHUNK + j] = f2bf((j <= i) ? sc * accW[mt][reg] : 0.f);
            }
    }

    // ---- RHS = [ B*V | B*eG*K ] (f32) ----
    {
        const int r  = t >> 2;
        const int c0 = (t & 3) * 32;
        const float be  = sBs[r];
        const float beg = be * sEG[r];
        const unsigned short* gv = qkv + (bL + l0 + r) * CONV_DIM + VOFF + c0;
#pragma unroll
        for (int u = 0; u < 4; ++u) {
            uint4 vv = *(const uint4*)(gv + 8 * u);
            const unsigned short* vp = (const unsigned short*)&vv;
#pragma unroll
            for (int e = 0; e < 8; ++e)
                sRHS[r * RSR1 + c0 + 8 * u + e] = be * bf2f(vp[e]);
        }
#pragma unroll
        for (int u = 0; u < 4; ++u)
#pragma unroll
            for (int e = 0; e < 8; ++e)
                sRHS[r * RSR1 + 128 + c0 + 8 * u + e] =
                    beg * bf2f(sKs[r * RSK + c0 + 8 * u + e]);
    }
    __syncthreads();   // Ks/Qs reads done -> DT overlay writable

    // zero X^T staging (padding rows read by block-solve MFMAs)
    for (int u = t; u < 256 * RSTD / 2; u += 256) ((uint32_t*)sDT)[u] = 0;

    // ---- blocked forward substitution, 256 columns ----
    float* Up = Ubuf + (size_t)bid * (CHUNK * DV);
    for (int sb = 0; sb < 4; ++sb) {
        const int sb16 = 16 * sb;
        if (sb > 0) {
            const int kbn = (sb + 1) >> 1;
            ffrag c16[4];
#pragma unroll
            for (int nt = 0; nt < 4; ++nt) c16[nt] = (ffrag)0.f;
            for (int kb = 0; kb < kbn; ++kb) {
                bfrag af = *(const bfrag*)&sAf[(sb16 + l16) * RST + 32 * kb + quad8];
#pragma unroll
                for (int nt = 0; nt < 4; ++nt) {
                    bfrag bf = *(const bfrag*)&sDT[(64 * w + 16 * nt + l16) * RSTD + 32 * kb + quad8];
                    c16[nt] = __builtin_amdgcn_mfma_f32_16x16x32_bf16(af, bf, c16[nt], 0, 0, 0);
                }
            }
#pragma unroll
            for (int nt = 0; nt < 4; ++nt)
#pragma unroll
                for (int reg = 0; reg < 4; ++reg)
                    sRHS[(sb16 + quad * 4 + reg) * RSR1 + 64 * w + 16 * nt + l16] -= c16[nt][reg];
        }
        __syncthreads();
        {   // serial 16x16 unit-lower solve; thread t owns column t
            const int c = t;
            float d16[16];
#pragma unroll
            for (int e = 0; e < 16; ++e) {
                const int i = sb16 + e;
                float acc = sRHS[i * RSR1 + c];
#pragma unroll
                for (int f = 0; f < 16; ++f)
                    if (f < e) acc -= bf2f(sAf[i * RST + sb16 + f]) * d16[f];
                d16[e] = acc;
            }
#pragma unroll
            for (int e = 0; e < 16; e += 2)
                *(uint32_t*)&sDT[c * RSTD + sb16 + e] = pk2(d16[e], d16[e + 1]);
            if (c < 128) {
                float* up = Up + c;
#pragma unroll
                for (int e = 0; e < 16; ++e) up[(size_t)(sb16 + e) * DV] = d16[e];
            } else {
                unsigned short* wp = qkv + (bL + l0 + sb16) * CONV_DIM + VOFF + (c - 128);
#pragma unroll
                for (int e = 0; e < 16; ++e) wp[(size_t)e * CONV_DIM] = f2bf(-d16[e]);
            }
        }
        __syncthreads();
    }
}

// ---- pass-2 LDS layout ----
constexpr int P2_oSTb = 0;                         // 128*136*2 = 34816
constexpr int P2_oWk  = P2_oSTb + 128 * RSK * 2;   // 34816 (+17408)
constexpr int P2_oQs  = P2_oWk + 64 * RSK * 2;     // 52224 (+17408)
constexpr int P2_oKT  = P2_oQs + 64 * RSK * 2;     // 69632 (+18432)
constexpr int P2_oWqk = P2_oKT + 128 * RST * 2;    // 88064 (+9216)
constexpr int P2_oDT  = P2_oWqk + 64 * RST * 2;    // 97280 (+18432)
constexpr int P2_oDdT = P2_oDT + 128 * RST * 2;    // 115712 (+18432) -> 134144
constexpr int P2_oU   = P2_oDT;                    // overlay DT+DdT (64*132*4 = 33792 <= 36864)
constexpr int P2_oEG  = P2_oDdT + 128 * RST * 2;   // 134144
constexpr int P2_oEGd = P2_oEG + 256;              // 134400
constexpr int P2_oNW  = P2_oEGd + 256;             // 134656
constexpr int P2_SMEM = P2_oNW + 512;              // 135168

__global__ __launch_bounds__(256, 1) void chunk_scan2(
    const unsigned short* __restrict__ qkv,   // q,k raw; v-slot holds Wkn
    const float* __restrict__ glog,
    const float* __restrict__ Ubuf,
    const unsigned short* __restrict__ Wqkbuf,
    unsigned short* __restrict__ z_io,
    const float* __restrict__ norm_w)
{
    extern __shared__ __align__(16) char smem[];
    unsigned short* sSTb = (unsigned short*)(smem + P2_oSTb);
    unsigned short* sWk  = (unsigned short*)(smem + P2_oWk);
    unsigned short* sQs  = (unsigned short*)(smem + P2_oQs);
    unsigned short* sKT  = (unsigned short*)(smem + P2_oKT);
    unsigned short* sWqk = (unsigned short*)(smem + P2_oWqk);
    unsigned short* sDT  = (unsigned short*)(smem + P2_oDT);
    unsigned short* sDdT = (unsigned short*)(smem + P2_oDdT);
    float* sU   = (float*)(smem + P2_oU);
    float* sEG  = (float*)(smem + P2_oEG);
    float* sEGd = (float*)(smem + P2_oEGd);
    float* sNW  = (float*)(smem + P2_oNW);

    const int bb = blockIdx.x >> 5;
    const int h  = blockIdx.x & (HV - 1);
    const int hk = h >> 1;
    const int t    = threadIdx.x;
    const int w    = t >> 6;
    const int lane = t & 63;
    const int quad = lane >> 4;
    const int l16  = lane & 15;
    const int quad8 = quad * 8;
    const size_t bL = (size_t)bb * L;
    const int VOFF = 2 * KEY_DIM + h * DV;
    const size_t chbase0 = ((size_t)bb * HV + h) * NCHUNK;

    // persistent state: ST[dv][dk], wave w owns dv in [32w,32w+32)
    ffrag accS[2][8];
#pragma unroll
    for (int mt = 0; mt < 2; ++mt)
#pragma unroll
        for (int nt = 0; nt < 8; ++nt) accS[mt][nt] = (ffrag)0.f;

    for (int u = t; u < 64 * RSK; u += 256) ((uint32_t*)sSTb)[u] = 0;  // 128*136 bf16
    if (t < 128) sNW[t] = norm_w[t];

    for (int ch = 0; ch < NCHUNK; ++ch) {
        const int l0 = ch * CHUNK;
        const size_t cb = chbase0 + ch;
        __syncthreads();   // A: prev STb written; all prev-phase LDS reads done

        // ---- load phase ----
        {
            const int r  = t >> 2;
            const int c0 = (t & 3) * 32;
            const unsigned short* grow = qkv + (bL + l0 + r) * CONV_DIM;
            const unsigned short* gq = grow + hk * DK + c0;
            const unsigned short* gk = grow + KEY_DIM + hk * DK + c0;
            const unsigned short* gw = grow + VOFF + c0;
#pragma unroll
            for (int u = 0; u < 4; ++u) {
                uint4 kv = *(const uint4*)(gk + 8 * u);
                *(uint4*)&sQs[r * RSK + c0 + 8 * u] = *(const uint4*)(gq + 8 * u);
                *(uint4*)&sWk[r * RSK + c0 + 8 * u] = *(const uint4*)(gw + 8 * u);
                const unsigned short* kp = (const unsigned short*)&kv;
#pragma unroll
                for (int e = 0; e < 8; ++e)
                    sKT[(c0 + 8 * u + e) * RST + r] = kp[e];
            }
            const float* up = Ubuf + cb * (CHUNK * DV) + r * DV + c0;
#pragma unroll
            for (int u = 0; u < 8; ++u)
                *(float4*)&sU[r * RSR2 + c0 + 4 * u] = *(const float4*)(up + 4 * u);
            const int cw = (t & 3) * 16;
            const unsigned short* qp = Wqkbuf + cb * (CHUNK * CHUNK) + r * CHUNK + cw;
#pragma unroll
            for (int u = 0; u < 2; ++u)
                *(uint4*)&sWqk[r * RST + cw + 8 * u] = *(const uint4*)(qp + 8 * u);
            if (t < 64) {
                float gl = glog[(bL + l0 + t) * HV + h];
#pragma unroll
                for (int off = 1; off < 64; off <<= 1) {
                    float v = __shfl_up(gl, off, 64);
                    if (lane >= off) gl += v;
                }
                float gc = __shfl(gl, 63, 64);
                sEG[t]  = __expf(gl);
                sEGd[t] = __expf(gc - gl);
            }
        }
        __syncthreads();   // B

        // ---- Delta = U + Wkn . ST (wave w: dv in [32w,32w+32)) ----
        ffrag accD[4][2];
#pragma unroll
        for (int mt = 0; mt < 4; ++mt)
#pragma unroll
            for (int nt = 0; nt < 2; ++nt)
#pragma unroll
                for (int reg = 0; reg < 4; ++reg)
                    accD[mt][nt][reg] =
                        sU[(16 * mt + quad * 4 + reg) * RSR2 + 32 * w + 16 * nt + l16];
#pragma unroll
        for (int kk = 0; kk < 4; ++kk) {
            bfrag b0 = *(const bfrag*)&sSTb[(32 * w + l16) * RSK + 32 * kk + quad8];
            bfrag b1 = *(const bfrag*)&sSTb[(32 * w + 16 + l16) * RSK + 32 * kk + quad8];
#pragma unroll
            for (int mt = 0; mt < 4; ++mt) {
                bfrag af = *(const bfrag*)&sWk[(16 * mt + l16) * RSK + 32 * kk + quad8];
                accD[mt][0] = __builtin_amdgcn_mfma_f32_16x16x32_bf16(af, b0, accD[mt][0], 0, 0, 0);
                accD[mt][1] = __builtin_amdgcn_mfma_f32_16x16x32_bf16(af, b1, accD[mt][1], 0, 0, 0);
            }
        }
        __syncthreads();   // C: sU reads done -> DT/DdT overlay writable

        // ---- write Delta^T and decayed Delta^T ----
#pragma unroll
        for (int mt = 0; mt < 4; ++mt)
#pragma unroll
            for (int nt = 0; nt < 2; ++nt) {
                const int dv = 32 * w + 16 * nt + l16;
#pragma unroll
                for (int reg = 0; reg < 4; ++reg) {
                    const int i = 16 * mt + quad * 4 + reg;
                    float d = accD[mt][nt][reg];
                    sDT[dv * RST + i]  = f2bf(d);
                    sDdT[dv * RST + i] = f2bf(d * sEGd[i]);
                }
            }
        __syncthreads();   // D

        // ---- O = eG*(Q ST) + Wqk . Delta ; epilogue ; state update ----
        {
            ffrag accO[8];
#pragma unroll
            for (int nt = 0; nt < 8; ++nt) accO[nt] = (ffrag)0.f;
#pragma unroll
            for (int kk = 0; kk < 4; ++kk) {
                bfrag af = *(const bfrag*)&sQs[(16 * w + l16) * RSK + 32 * kk + quad8];
#pragma unroll
                for (int nt = 0; nt < 8; ++nt) {
                    bfrag bf = *(const bfrag*)&sSTb[(16 * nt + l16) * RSK + 32 * kk + quad8];
                    accO[nt] = __builtin_amdgcn_mfma_f32_16x16x32_bf16(af, bf, accO[nt], 0, 0, 0);
                }
            }
#pragma unroll
            for (int nt = 0; nt < 8; ++nt)
#pragma unroll
                for (int reg = 0; reg < 4; ++reg)
                    accO[nt][reg] *= sEG[16 * w + quad * 4 + reg];
#pragma unroll
            for (int kk = 0; kk < 2; ++kk) {
                bfrag af = *(const bfrag*)&sWqk[(16 * w + l16) * RST + 32 * kk + quad8];
#pragma unroll
                for (int nt = 0; nt < 8; ++nt) {
                    bfrag bf = *(const bfrag*)&sDT[(16 * nt + l16) * RST + 32 * kk + quad8];
                    accO[nt] = __builtin_amdgcn_mfma_f32_16x16x32_bf16(af, bf, accO[nt], 0, 0, 0);
                }
            }
            // RMSNorm over dv + silu(z) gate, write y over z
            float inv[4];
#pragma unroll
            for (int reg = 0; reg < 4; ++reg) {
                float p = 0.f;
#pragma unroll
                for (int nt = 0; nt < 8; ++nt) p += accO[nt][reg] * accO[nt][reg];
#pragma unroll
                for (int m = 1; m < 16; m <<= 1) p += __shfl_xor(p, m, 64);
                inv[reg] = rsqrtf(p * (1.f / 128.f) + EPS);
            }
            const int i0 = 16 * w + quad * 4;
#pragma unroll
            for (int nt = 0; nt < 8; ++nt) {
                const int dv = 16 * nt + l16;
                const float nwv = sNW[dv];
#pragma unroll
                for (int reg = 0; reg < 4; ++reg) {
                    size_t zi = (bL + l0 + i0 + reg) * (size_t)VAL_DIM + h * DV + dv;
                    float zv = bf2f(z_io[zi]);
                    float y = accO[nt][reg] * inv[reg] * nwv * (zv / (1.f + __expf(-zv)));
                    z_io[zi] = f2bf(y);
                }
            }

            // state update: ST = eGc*ST + DdT . KT
            const float eGc = sEG[63];
#pragma unroll
            for (int mt = 0; mt < 2; ++mt)
#pragma unroll
                for (int nt = 0; nt < 8; ++nt)
#pragma unroll
                    for (int reg = 0; reg < 4; ++reg) accS[mt][nt][reg] *= eGc;
#pragma unroll
            for (int kk = 0; kk < 2; ++kk) {
                bfrag a0 = *(const bfrag*)&sDdT[(32 * w + l16) * RST + 32 * kk + quad8];
                bfrag a1 = *(const bfrag*)&sDdT[(32 * w + 16 + l16) * RST + 32 * kk + quad8];
#pragma unroll
                for (int nt = 0; nt < 8; ++nt) {
                    bfrag bk = *(const bfrag*)&sKT[(16 * nt + l16) * RST + 32 * kk + quad8];
                    accS[0][nt] = __builtin_amdgcn_mfma_f32_16x16x32_bf16(a0, bk, accS[0][nt], 0, 0, 0);
                    accS[1][nt] = __builtin_amdgcn_mfma_f32_16x16x32_bf16(a1, bk, accS[1][nt], 0, 0, 0);
                }
            }
        }
        __syncthreads();   // E: all STb/DT/DdT/KT reads done

        // ---- materialize STb (bf16) for next chunk ----
#pragma unroll
        for (int mt = 0; mt < 2; ++mt)
#pragma unroll
            for (int nt = 0; nt < 8; ++nt)
#pragma unroll
                for (int reg = 0; reg < 4; ++reg)
                    sSTb[(32 * w + 16 * mt + quad * 4 + reg) * RSK + 16 * nt + l16] =
                        f2bf(accS[mt][nt][reg]);
    }
}

// ---------------- launch ----------------
extern "C" void kernel_launch(void* const* d_in, const int* in_sizes, int n_in,
                              void* d_out, int out_size, void* d_ws, size_t ws_size,
                              hipStream_t stream)
{
    const float* x        = (const float*)d_in[0];
    const float* W_qkv    = (const float*)d_in[1];
    const float* W_z      = (const float*)d_in[2];
    const float* W_a      = (const float*)d_in[3];
    const float* W_b      = (const float*)d_in[4];
    const float* conv_w   = (const float*)d_in[5];
    const float* A_log    = (const float*)d_in[6];
    const float* dt_bias  = (const float*)d_in[7];
    const float* norm_w   = (const float*)d_in[8];
    const float* W_out    = (const float*)d_in[9];
    float* out = (float*)d_out;
    char*  ws  = (char*)d_ws;

    if (ws_size < WS_NEED_BYTES) return;

    unsigned short* qkv = (unsigned short*)(ws + OFF_QKV);
    unsigned short* z   = (unsigned short*)(ws + OFF_Z);
    float* a    = (float*)(ws + OFF_A);
    float* bbuf = (float*)(ws + OFF_B);
    float* gl   = (float*)(ws + OFF_G);
    float* beta = (float*)(ws + OFF_BETA);
    float* Ubuf = (float*)(ws + OFF_U);
    unsigned short* Wqkbuf = (unsigned short*)(ws + OFF_WQK);
    unsigned short* Wcat   = (unsigned short*)(ws + OFF_WCAT);  // overlay on U
    unsigned short* xb     = (unsigned short*)(ws + OFF_XB);    // overlay on Wqk
    unsigned short* Wob    = (unsigned short*)(ws + OFF_WOB);   // overlay on U

    static bool attr_set = false;
    if (!attr_set) {
        (void)hipFuncSetAttribute((const void*)chunk_prep,
                                  hipFuncAttributeMaxDynamicSharedMemorySize, P1_SMEM);
        (void)hipFuncSetAttribute((const void*)chunk_scan2,
                                  hipFuncAttributeMaxDynamicSharedMemorySize, P2_SMEM);
        attr_set = true;
    }

    // 0. pre-convert operands to bf16 (Wcat overlays U-region, xb overlays Wqk-region)
    cvt_wcat<<<NPAD, 256, 0, stream>>>(W_qkv, W_z, W_a, W_b, Wcat);
    cvt_f32bf<<<(int)ROWS, 256, 0, stream>>>(x, xb, DIM);
    // 1. fused input projections (bf16 MFMA GEMM, global_load_lds)
    gemm_inproj_bf<<<(NPAD / 128) * 32, 256, 0, stream>>>(xb, Wcat, qkv, z, a, bbuf);
    // 2. depthwise causal conv + silu
    conv_silu<<<(B * CONV_DIM) / 256, 256, 0, stream>>>(qkv, conv_w);
    // 3. l2norm q,k heads
    normqk<<<(B * L * 2 * HK) / 4, 256, 0, stream>>>(qkv);
    // 4. gate coefficients (log-space g)
    gatecoef<<<(B * L * HV) / 256, 256, 0, stream>>>(a, bbuf, A_log, dt_bias, gl, beta);
    // 5a. parallel chunk prep: A, Wqk, solve -> U (f32, overwrites Wcat), Wkn (v-slot)
    chunk_prep<<<NCH_TOT, 256, P1_SMEM, stream>>>(qkv, gl, beta, Ubuf, Wqkbuf);
    // 5b. sequential scan: Delta/O/state + fused gated RMSNorm (y overwrites z)
    chunk_scan2<<<B * HV, 256, P2_SMEM, stream>>>(qkv, gl, Ubuf, Wqkbuf, z, norm_w);
    // 5c. convert W_out to bf16 (U dead now; overlay)
    cvt_f32bf<<<DIM, 256, 0, stream>>>(W_out, Wob, VAL_DIM);
    // 6. output projection (bf16 MFMA GEMM)
    gemm_outproj_bf<<<(DIM / 128) * 32, 256, 0, stream>>>(z, Wob, out);
}